// Round 1
// baseline (303.752 us; speedup 1.0000x reference)
//
#include <hip/hip_runtime.h>
#include <math.h>

// Problem constants (CantorAttention): B=2, S=2048, DIM=512, H=8, HD=64, K=64
#define B_    2
#define S_    2048
#define DIM_  512
#define H_    8
#define HD_   64
#define K_    64
#define M_    (B_ * S_)          // 4096 rows of x
#define NQKV_ (3 * DIM_)         // 1536
static constexpr float SCALE_ = 0.125f;  // 1/sqrt(64)

// ---------------------------------------------------------------------------
// Tiled fp32 GEMM: C[M,N] = A[M,Kd] * W[Kd,N] + bias[N]
// 64x64 block tile, BK=16, 256 threads, 4x4 accum per thread.
// mode 0: plain row-major C output.
// mode 1: qkv scatter — column n = which*512 + h*64 + d; each 64-wide column
//         tile has fixed (which,h), so stores are contiguous float4 in d.
// ---------------------------------------------------------------------------
__global__ __launch_bounds__(256) void gemm64(
    const float* __restrict__ A, const float* __restrict__ W,
    const float* __restrict__ bias, float* __restrict__ C,
    float* __restrict__ Q, float* __restrict__ Kp, float* __restrict__ V,
    int N, int Kd, int mode)
{
    __shared__ float As[16][64 + 4];  // [kk][m], +4 keeps rows 16B-aligned
    __shared__ float Ws[16][64 + 4];  // [kk][n]

    const int t  = threadIdx.x;
    const int m0 = blockIdx.y * 64;
    const int n0 = blockIdx.x * 64;
    const int tx = t & 15;            // 16 cols of threads
    const int ty = t >> 4;            // 16 rows of threads

    float acc[4][4] = {};

    for (int k0 = 0; k0 < Kd; k0 += 16) {
        // --- A tile 64x16: one float4 along K per thread, transpose into As[kk][m]
        {
            const int mm = t >> 2;          // 0..63
            const int kk = (t & 3) * 4;     // 0,4,8,12
            float4 av = *(const float4*)&A[(size_t)(m0 + mm) * Kd + k0 + kk];
            As[kk + 0][mm] = av.x;
            As[kk + 1][mm] = av.y;
            As[kk + 2][mm] = av.z;
            As[kk + 3][mm] = av.w;
        }
        // --- W tile 16x64: one float4 along N per thread
        {
            const int kk = t >> 4;          // 0..15
            const int nn = (t & 15) * 4;    // 0..60
            float4 wv = *(const float4*)&W[(size_t)(k0 + kk) * N + n0 + nn];
            *(float4*)&Ws[kk][nn] = wv;
        }
        __syncthreads();

        #pragma unroll
        for (int kk = 0; kk < 16; ++kk) {
            float4 av = *(const float4*)&As[kk][ty * 4];
            float4 bv = *(const float4*)&Ws[kk][tx * 4];
            float a[4] = {av.x, av.y, av.z, av.w};
            float b[4] = {bv.x, bv.y, bv.z, bv.w};
            #pragma unroll
            for (int i = 0; i < 4; ++i)
                #pragma unroll
                for (int j = 0; j < 4; ++j)
                    acc[i][j] += a[i] * b[j];
        }
        __syncthreads();
    }

    // epilogue: bias + store (float4 per row)
    float4 bv = *(const float4*)&bias[n0 + tx * 4];

    if (mode == 0) {
        #pragma unroll
        for (int i = 0; i < 4; ++i) {
            const int m = m0 + ty * 4 + i;
            float4 o;
            o.x = acc[i][0] + bv.x;
            o.y = acc[i][1] + bv.y;
            o.z = acc[i][2] + bv.z;
            o.w = acc[i][3] + bv.w;
            *(float4*)&C[(size_t)m * N + n0 + tx * 4] = o;
        }
    } else {
        const int which = n0 >> 9;          // 0=q 1=k 2=v
        const int h     = (n0 >> 6) & 7;
        float* dst = (which == 0) ? Q : (which == 1 ? Kp : V);
        #pragma unroll
        for (int i = 0; i < 4; ++i) {
            const int m = m0 + ty * 4 + i;
            const int b = m >> 11;          // m / 2048
            const int s = m & 2047;
            float4 o;
            o.x = acc[i][0] + bv.x;
            o.y = acc[i][1] + bv.y;
            o.z = acc[i][2] + bv.z;
            o.w = acc[i][3] + bv.w;
            *(float4*)&dst[(((size_t)b * H_ + h) * S_ + s) * HD_ + tx * 4] = o;
        }
    }
}

// ---------------------------------------------------------------------------
// Gathered attention: one wave (64 lanes) per query (b,h,s).
// Phase 1: lane j = key j; dot(q, K[routes[s][j]]) via per-lane float4 row.
// Softmax: 64-lane shuffle reductions.
// Phase 2: lane = d; sum_j w[j] * V[routes[s][j]][d] — coalesced across lanes.
// ---------------------------------------------------------------------------
__global__ __launch_bounds__(256) void attn_kernel(
    const float* __restrict__ Q, const float* __restrict__ Kp,
    const float* __restrict__ V, const int* __restrict__ routes,
    float* __restrict__ attn)
{
    __shared__ float q_s[4][64];
    __shared__ float w_s[4][64];
    __shared__ int   r_s[4][64];

    const int wv   = threadIdx.x >> 6;
    const int lane = threadIdx.x & 63;
    const int qi   = blockIdx.x * 4 + wv;      // (b*H + h)*S + s, s fastest
    const int bh   = qi >> 11;                 // b*H + h
    const int s    = qi & 2047;
    const int b    = qi >> 14;
    const int h    = (qi >> 11) & 7;

    q_s[wv][lane] = Q[((size_t)bh * S_ + s) * HD_ + lane];
    r_s[wv][lane] = routes[s * K_ + lane];
    __syncthreads();

    // phase 1: score for key `lane`
    const int r = r_s[wv][lane];
    const float* kp = Kp + ((size_t)bh * S_ + r) * HD_;
    float sc = 0.f;
    #pragma unroll
    for (int d = 0; d < 64; d += 4) {
        float4 kv = *(const float4*)(kp + d);
        sc += q_s[wv][d + 0] * kv.x + q_s[wv][d + 1] * kv.y
            + q_s[wv][d + 2] * kv.z + q_s[wv][d + 3] * kv.w;
    }
    sc *= SCALE_;

    float mx = sc;
    #pragma unroll
    for (int off = 32; off >= 1; off >>= 1)
        mx = fmaxf(mx, __shfl_xor(mx, off));
    float e = __expf(sc - mx);
    float sum = e;
    #pragma unroll
    for (int off = 32; off >= 1; off >>= 1)
        sum += __shfl_xor(sum, off);
    w_s[wv][lane] = e / sum;
    __syncthreads();

    // phase 2: output element d = lane
    const float* vbase = V + (size_t)bh * S_ * HD_;
    float acc = 0.f;
    #pragma unroll 8
    for (int j = 0; j < 64; ++j) {
        const int rj = r_s[wv][j];
        acc += w_s[wv][j] * vbase[(size_t)rj * HD_ + lane];
    }
    attn[((size_t)b * S_ + s) * DIM_ + h * HD_ + lane] = acc;
}

// ---------------------------------------------------------------------------
// Workspace layout (floats):
//   Q    [B*H*S*HD] = 2,097,152   @ 0
//   K    [B*H*S*HD] = 2,097,152   @ 2,097,152
//   V    [B*H*S*HD] = 2,097,152   @ 4,194,304
//   attn [B*S*DIM]  = 2,097,152   @ 6,291,456
// total 32 MB
// ---------------------------------------------------------------------------
extern "C" void kernel_launch(void* const* d_in, const int* in_sizes, int n_in,
                              void* d_out, int out_size, void* d_ws, size_t ws_size,
                              hipStream_t stream)
{
    const float* x     = (const float*)d_in[0];
    const float* Wqkv  = (const float*)d_in[1];
    const float* bqkv  = (const float*)d_in[2];
    const float* Wout  = (const float*)d_in[3];
    const float* bout  = (const float*)d_in[4];
    const int*   routes = (const int*)d_in[5];

    float* ws   = (float*)d_ws;
    float* Q    = ws;
    float* Kp   = ws + 2097152;
    float* V    = ws + 4194304;
    float* attn = ws + 6291456;
    float* out  = (float*)d_out;

    dim3 blk(256);

    // qkv projection + scatter to [B,H,S,HD]
    gemm64<<<dim3(NQKV_ / 64, M_ / 64), blk, 0, stream>>>(
        x, Wqkv, bqkv, nullptr, Q, Kp, V, NQKV_, DIM_, 1);

    // gathered attention
    attn_kernel<<<dim3((B_ * H_ * S_) / 4), blk, 0, stream>>>(
        Q, Kp, V, routes, attn);

    // output projection
    gemm64<<<dim3(DIM_ / 64, M_ / 64), blk, 0, stream>>>(
        attn, Wout, bout, out, nullptr, nullptr, nullptr, DIM_, DIM_, 0);
}

// Round 2
// 174.678 us; speedup vs baseline: 1.7389x; 1.7389x over previous
//
#include <hip/hip_runtime.h>
#include <math.h>

// CantorAttention: B=2, S=2048, DIM=512, H=8, HD=64, K=64
#define B_    2
#define S_    2048
#define DIM_  512
#define H_    8
#define HD_   64
#define K_    64
#define M_    (B_ * S_)          // 4096
#define NQKV_ (3 * DIM_)         // 1536

typedef __attribute__((ext_vector_type(8))) short          short8;    // mfma A/B frag (8 bf16)
typedef __attribute__((ext_vector_type(8))) unsigned short ushort8v;  // 16B LDS/global move
typedef __attribute__((ext_vector_type(4))) float          float4v;   // mfma C/D frag

// ---- bf16 split helpers (RN-even) ------------------------------------------
__device__ __forceinline__ unsigned short f2bf_rn(float f) {
    unsigned int u = __float_as_uint(f);
    return (unsigned short)((u + 0x7FFFu + ((u >> 16) & 1u)) >> 16);
}
__device__ __forceinline__ float bf2f(unsigned short h) {
    return __uint_as_float((unsigned int)h << 16);
}

// ---------------------------------------------------------------------------
// prep_x: elementwise split fp32 -> (hi, lo) bf16 arrays. 8 elems/thread.
// ---------------------------------------------------------------------------
__global__ __launch_bounds__(256) void prep_x(const float* __restrict__ X,
                                              unsigned short* __restrict__ Hi,
                                              unsigned short* __restrict__ Lo)
{
    size_t i = ((size_t)blockIdx.x * 256 + threadIdx.x) * 8;
    float4 a = *(const float4*)&X[i];
    float4 b = *(const float4*)&X[i + 4];
    float f[8] = {a.x, a.y, a.z, a.w, b.x, b.y, b.z, b.w};
    ushort8v h, l;
    #pragma unroll
    for (int j = 0; j < 8; ++j) {
        unsigned short hh = f2bf_rn(f[j]);
        h[j] = hh;
        l[j] = f2bf_rn(f[j] - bf2f(hh));
    }
    *(ushort8v*)&Hi[i] = h;
    *(ushort8v*)&Lo[i] = l;
}

// ---------------------------------------------------------------------------
// prep_w: transpose + split W[Kd][N] fp32 -> Whi/Wlo [N][Kd] bf16.
// 32x32 LDS tile; coalesced read and write.
// ---------------------------------------------------------------------------
__global__ __launch_bounds__(256) void prep_w(const float* __restrict__ W,
                                              unsigned short* __restrict__ Whi,
                                              unsigned short* __restrict__ Wlo,
                                              int Kd, int N)
{
    __shared__ float tile[32][33];
    const int k0 = blockIdx.y * 32, n0 = blockIdx.x * 32;
    const int c = threadIdx.x & 31, r8 = threadIdx.x >> 5;
    #pragma unroll
    for (int i = 0; i < 4; ++i) {
        int r = r8 + i * 8;
        tile[r][c] = W[(size_t)(k0 + r) * N + n0 + c];
    }
    __syncthreads();
    #pragma unroll
    for (int i = 0; i < 4; ++i) {
        int r = r8 + i * 8;                 // n offset
        float f = tile[c][r];               // = W[k0+c][n0+r]
        unsigned short hi = f2bf_rn(f);
        unsigned short lo = f2bf_rn(f - bf2f(hi));
        Whi[(size_t)(n0 + r) * Kd + k0 + c] = hi;
        Wlo[(size_t)(n0 + r) * Kd + k0 + c] = lo;
    }
}

// ---------------------------------------------------------------------------
// Split-bf16 MFMA GEMM: C[M,N] = A[M,Kd]*W[Kd,N] + bias, fp32-equivalent via
// 3 MFMAs (hi*hi + lo*hi + hi*lo). A pre-split row-major [m][k]; W pre-split
// transposed [n][k]. 16x16x32 bf16 MFMA.
//   mode 0: row-major C.  mode 1: qkv scatter into Q/K/V [B,H,S,HD].
// ---------------------------------------------------------------------------
template<int BM, int BN, int WM, int WN>
__global__ __launch_bounds__(256) void gemm_mfma(
    const unsigned short* __restrict__ Ahi, const unsigned short* __restrict__ Alo,
    const unsigned short* __restrict__ Whi, const unsigned short* __restrict__ Wlo,
    const float* __restrict__ bias, float* __restrict__ C,
    float* __restrict__ Qo, float* __restrict__ Ko, float* __restrict__ Vo,
    int N, int Kd, int mode)
{
    constexpr int TM = WM / 16, TN = WN / 16;
    constexpr int WAVES_N = BN / WN;
    constexpr int LDK = 40;   // 32 + 8 pad; rows stay 16B-aligned (80B stride)
    __shared__ unsigned short Ah[BM][LDK], Al[BM][LDK];
    __shared__ unsigned short Bh[BN][LDK], Bl[BN][LDK];

    const int t = threadIdx.x, lane = t & 63, wave = t >> 6;
    const int wm = (wave / WAVES_N) * WM, wn = (wave % WAVES_N) * WN;
    const int m0 = blockIdx.y * BM, n0 = blockIdx.x * BN;
    const int l15 = lane & 15, l4 = lane >> 4;

    float4v acc[TM][TN];
    #pragma unroll
    for (int i = 0; i < TM; ++i)
        #pragma unroll
        for (int j = 0; j < TN; ++j)
            #pragma unroll
            for (int r = 0; r < 4; ++r) acc[i][j][r] = 0.f;

    for (int k0 = 0; k0 < Kd; k0 += 32) {
        constexpr int ACH = BM * 4 / 256;   // 16B chunks per thread for A
        #pragma unroll
        for (int i = 0; i < ACH; ++i) {
            int idx = t + i * 256;
            int m = idx >> 2, cc = (idx & 3) * 8;
            size_t g = (size_t)(m0 + m) * Kd + k0 + cc;
            *(ushort8v*)&Ah[m][cc] = *(const ushort8v*)&Ahi[g];
            *(ushort8v*)&Al[m][cc] = *(const ushort8v*)&Alo[g];
        }
        constexpr int BCH = BN * 4 / 256;
        #pragma unroll
        for (int i = 0; i < BCH; ++i) {
            int idx = t + i * 256;
            int n = idx >> 2, cc = (idx & 3) * 8;
            size_t g = (size_t)(n0 + n) * Kd + k0 + cc;
            *(ushort8v*)&Bh[n][cc] = *(const ushort8v*)&Whi[g];
            *(ushort8v*)&Bl[n][cc] = *(const ushort8v*)&Wlo[g];
        }
        __syncthreads();

        short8 fa_h[TM], fa_l[TM], fb_h[TN], fb_l[TN];
        #pragma unroll
        for (int im = 0; im < TM; ++im) {
            fa_h[im] = *(const short8*)&Ah[wm + im * 16 + l15][l4 * 8];
            fa_l[im] = *(const short8*)&Al[wm + im * 16 + l15][l4 * 8];
        }
        #pragma unroll
        for (int in = 0; in < TN; ++in) {
            fb_h[in] = *(const short8*)&Bh[wn + in * 16 + l15][l4 * 8];
            fb_l[in] = *(const short8*)&Bl[wn + in * 16 + l15][l4 * 8];
        }
        #pragma unroll
        for (int im = 0; im < TM; ++im)
            #pragma unroll
            for (int in = 0; in < TN; ++in) {
                acc[im][in] = __builtin_amdgcn_mfma_f32_16x16x32_bf16(fa_h[im], fb_h[in], acc[im][in], 0, 0, 0);
                acc[im][in] = __builtin_amdgcn_mfma_f32_16x16x32_bf16(fa_l[im], fb_h[in], acc[im][in], 0, 0, 0);
                acc[im][in] = __builtin_amdgcn_mfma_f32_16x16x32_bf16(fa_h[im], fb_l[in], acc[im][in], 0, 0, 0);
            }
        __syncthreads();
    }

    // epilogue: D row = (lane>>4)*4 + reg, col = lane&15  [m89-verified layout]
    if (mode == 0) {
        #pragma unroll
        for (int in = 0; in < TN; ++in) {
            int n = n0 + wn + in * 16 + l15;
            float bv = bias[n];
            #pragma unroll
            for (int im = 0; im < TM; ++im) {
                int mb = m0 + wm + im * 16 + l4 * 4;
                #pragma unroll
                for (int r = 0; r < 4; ++r)
                    C[(size_t)(mb + r) * N + n] = acc[im][in][r] + bv;
            }
        }
    } else {
        #pragma unroll
        for (int in = 0; in < TN; ++in) {
            int n = n0 + wn + in * 16 + l15;
            int which = n >> 9, h = (n >> 6) & 7, d = n & 63;
            float* dst = (which == 0) ? Qo : (which == 1 ? Ko : Vo);
            float bv = bias[n];
            #pragma unroll
            for (int im = 0; im < TM; ++im) {
                int mb = m0 + wm + im * 16 + l4 * 4;
                #pragma unroll
                for (int r = 0; r < 4; ++r) {
                    int m = mb + r, b = m >> 11, s = m & 2047;
                    dst[(((size_t)b * H_ + h) * S_ + s) * HD_ + d] = acc[im][in][r] + bv;
                }
            }
        }
    }
}

// ---------------------------------------------------------------------------
// Gathered attention, one wave per query. Phase 1: 4 lanes per key (64B
// contiguous per lane) + quad shuffle reduce. Phase 2: lane=d, coalesced V
// rows. Output written pre-split (hi/lo bf16) for the out-projection GEMM.
// ---------------------------------------------------------------------------
__global__ __launch_bounds__(256) void attn_kernel(
    const float* __restrict__ Q, const float* __restrict__ Kp,
    const float* __restrict__ V, const int* __restrict__ routes,
    unsigned short* __restrict__ Ohi, unsigned short* __restrict__ Olo)
{
    __shared__ float q_s[4][64];
    __shared__ float w_s[4][64];
    __shared__ int   r_s[4][64];

    const int wv = threadIdx.x >> 6, lane = threadIdx.x & 63;
    const int qi = blockIdx.x * 4 + wv;       // (b*H+h)*S + s
    const int bh = qi >> 11, s = qi & 2047;
    const int b = qi >> 14, h = (qi >> 11) & 7;

    q_s[wv][lane] = Q[((size_t)bh * S_ + s) * HD_ + lane];
    r_s[wv][lane] = routes[s * K_ + lane];
    __syncthreads();

    // phase 1: scores. lane = (key quad p, key-in-pass jl)
    const int p = lane & 3, jl = lane >> 2;
    float qv[16];
    #pragma unroll
    for (int i = 0; i < 16; ++i) qv[i] = q_s[wv][p * 16 + i];

    const float* kbase = Kp + (size_t)bh * S_ * HD_;
    #pragma unroll
    for (int pass = 0; pass < 4; ++pass) {
        int j = pass * 16 + jl;
        int rj = r_s[wv][j];
        const float* kp = kbase + (size_t)rj * HD_ + p * 16;
        float partial = 0.f;
        #pragma unroll
        for (int i = 0; i < 16; i += 4) {
            float4 kv = *(const float4*)(kp + i);
            partial += qv[i] * kv.x + qv[i + 1] * kv.y + qv[i + 2] * kv.z + qv[i + 3] * kv.w;
        }
        partial += __shfl_xor(partial, 1);
        partial += __shfl_xor(partial, 2);
        if (p == 0) w_s[wv][j] = partial * 0.125f;
    }
    __syncthreads();

    // softmax over 64 keys (shuffle)
    float sc = w_s[wv][lane];
    float mx = sc;
    #pragma unroll
    for (int off = 32; off >= 1; off >>= 1) mx = fmaxf(mx, __shfl_xor(mx, off));
    float e = __expf(sc - mx);
    float sum = e;
    #pragma unroll
    for (int off = 32; off >= 1; off >>= 1) sum += __shfl_xor(sum, off);
    w_s[wv][lane] = e / sum;
    __syncthreads();

    // phase 2: output d = lane
    const float* vbase = V + (size_t)bh * S_ * HD_;
    float acc = 0.f;
    #pragma unroll 8
    for (int j = 0; j < 64; ++j)
        acc += w_s[wv][j] * vbase[(size_t)r_s[wv][j] * HD_ + lane];

    unsigned short hi = f2bf_rn(acc);
    unsigned short lo = f2bf_rn(acc - bf2f(hi));
    size_t oi = ((size_t)b * S_ + s) * DIM_ + h * HD_ + lane;
    Ohi[oi] = hi;
    Olo[oi] = lo;
}

// ---------------------------------------------------------------------------
// ws layout (bytes):
//   0        Q      8 MB (fp32 [B,H,S,HD])
//   8M       K      8 MB
//   16M      V      8 MB
//   24M      x_hi   4 MB (bf16)  -- reused as attn_hi after qkv gemm
//   28M      x_lo   4 MB         -- reused as attn_lo
//   32M      Wqkv_hi 1.5 MB ; +1.5M Wqkv_lo ; +3M Wout_hi 0.5 ; +3.5M Wout_lo
// total 36 MB
// ---------------------------------------------------------------------------
extern "C" void kernel_launch(void* const* d_in, const int* in_sizes, int n_in,
                              void* d_out, int out_size, void* d_ws, size_t ws_size,
                              hipStream_t stream)
{
    const float* x      = (const float*)d_in[0];
    const float* Wqkv   = (const float*)d_in[1];
    const float* bqkv   = (const float*)d_in[2];
    const float* Wout   = (const float*)d_in[3];
    const float* bout   = (const float*)d_in[4];
    const int*   routes = (const int*)d_in[5];
    float* out = (float*)d_out;

    char* w = (char*)d_ws;
    float* Q  = (float*)(w);
    float* Kp = (float*)(w + (8u << 20));
    float* V  = (float*)(w + (16u << 20));
    unsigned short* xh  = (unsigned short*)(w + (24u << 20));
    unsigned short* xl  = (unsigned short*)(w + (28u << 20));
    unsigned short* ah  = xh;   // aliased: free after qkv gemm
    unsigned short* al  = xl;
    unsigned short* wqh = (unsigned short*)(w + (32u << 20));
    unsigned short* wql = (unsigned short*)(w + (32u << 20) + 1572864u);
    unsigned short* woh = (unsigned short*)(w + (32u << 20) + 3145728u);
    unsigned short* wol = (unsigned short*)(w + (32u << 20) + 3670016u);

    dim3 blk(256);

    prep_x<<<dim3((M_ * DIM_) / (256 * 8)), blk, 0, stream>>>(x, xh, xl);
    prep_w<<<dim3(NQKV_ / 32, DIM_ / 32), blk, 0, stream>>>(Wqkv, wqh, wql, DIM_, NQKV_);
    prep_w<<<dim3(DIM_ / 32, DIM_ / 32), blk, 0, stream>>>(Wout, woh, wol, DIM_, DIM_);

    // qkv: M=4096, N=1536, K=512 -> 12 x 32 = 384 blocks
    gemm_mfma<128, 128, 64, 64><<<dim3(NQKV_ / 128, M_ / 128), blk, 0, stream>>>(
        xh, xl, wqh, wql, bqkv, nullptr, Q, Kp, V, NQKV_, DIM_, 1);

    attn_kernel<<<dim3((B_ * H_ * S_) / 4), blk, 0, stream>>>(Q, Kp, V, routes, ah, al);

    // out-proj: M=4096, N=512, K=512 -> 4 x 64 = 256 blocks
    gemm_mfma<64, 128, 64, 32><<<dim3(DIM_ / 128, M_ / 64), blk, 0, stream>>>(
        ah, al, woh, wol, bout, out, nullptr, nullptr, nullptr, DIM_, DIM_, 0);
}

// Round 3
// 170.614 us; speedup vs baseline: 1.7803x; 1.0238x over previous
//
#include <hip/hip_runtime.h>
#include <math.h>

// CantorAttention: B=2, S=2048, DIM=512, H=8, HD=64, K=64
#define B_    2
#define S_    2048
#define DIM_  512
#define H_    8
#define HD_   64
#define K_    64
#define M_    (B_ * S_)          // 4096
#define NQKV_ (3 * DIM_)         // 1536

typedef __attribute__((ext_vector_type(8))) short          short8;    // mfma A/B frag (8 bf16)
typedef __attribute__((ext_vector_type(8))) unsigned short ushort8v;  // 16B LDS/global move
typedef __attribute__((ext_vector_type(4))) float          float4v;   // mfma C/D frag

// ---- bf16 split helpers (RN-even) ------------------------------------------
__device__ __forceinline__ unsigned short f2bf_rn(float f) {
    unsigned int u = __float_as_uint(f);
    return (unsigned short)((u + 0x7FFFu + ((u >> 16) & 1u)) >> 16);
}
__device__ __forceinline__ float bf2f(unsigned short h) {
    return __uint_as_float((unsigned int)h << 16);
}

// ---------------------------------------------------------------------------
// prep_x: elementwise split fp32 -> (hi, lo) bf16 arrays. 8 elems/thread.
// ---------------------------------------------------------------------------
__global__ __launch_bounds__(256) void prep_x(const float* __restrict__ X,
                                              unsigned short* __restrict__ Hi,
                                              unsigned short* __restrict__ Lo)
{
    size_t i = ((size_t)blockIdx.x * 256 + threadIdx.x) * 8;
    float4 a = *(const float4*)&X[i];
    float4 b = *(const float4*)&X[i + 4];
    float f[8] = {a.x, a.y, a.z, a.w, b.x, b.y, b.z, b.w};
    ushort8v h, l;
    #pragma unroll
    for (int j = 0; j < 8; ++j) {
        unsigned short hh = f2bf_rn(f[j]);
        h[j] = hh;
        l[j] = f2bf_rn(f[j] - bf2f(hh));
    }
    *(ushort8v*)&Hi[i] = h;
    *(ushort8v*)&Lo[i] = l;
}

// ---------------------------------------------------------------------------
// prep_w: transpose + split W[Kd][N] fp32 -> Whi/Wlo [N][Kd] bf16.
// ---------------------------------------------------------------------------
__global__ __launch_bounds__(256) void prep_w(const float* __restrict__ W,
                                              unsigned short* __restrict__ Whi,
                                              unsigned short* __restrict__ Wlo,
                                              int Kd, int N)
{
    __shared__ float tile[32][33];
    const int k0 = blockIdx.y * 32, n0 = blockIdx.x * 32;
    const int c = threadIdx.x & 31, r8 = threadIdx.x >> 5;
    #pragma unroll
    for (int i = 0; i < 4; ++i) {
        int r = r8 + i * 8;
        tile[r][c] = W[(size_t)(k0 + r) * N + n0 + c];
    }
    __syncthreads();
    #pragma unroll
    for (int i = 0; i < 4; ++i) {
        int r = r8 + i * 8;                 // n offset
        float f = tile[c][r];               // = W[k0+c][n0+r]
        unsigned short hi = f2bf_rn(f);
        unsigned short lo = f2bf_rn(f - bf2f(hi));
        Whi[(size_t)(n0 + r) * Kd + k0 + c] = hi;
        Wlo[(size_t)(n0 + r) * Kd + k0 + c] = lo;
    }
}

// ---------------------------------------------------------------------------
// Split-bf16 MFMA GEMM (3 MFMAs: hi*hi + lo*hi + hi*lo).
//   mode 0: row-major C.  mode 1: qkv scatter into Q/K/V [B,H,S,HD].
// ---------------------------------------------------------------------------
template<int BM, int BN, int WM, int WN>
__global__ __launch_bounds__(256) void gemm_mfma(
    const unsigned short* __restrict__ Ahi, const unsigned short* __restrict__ Alo,
    const unsigned short* __restrict__ Whi, const unsigned short* __restrict__ Wlo,
    const float* __restrict__ bias, float* __restrict__ C,
    float* __restrict__ Qo, float* __restrict__ Ko, float* __restrict__ Vo,
    int N, int Kd, int mode)
{
    constexpr int TM = WM / 16, TN = WN / 16;
    constexpr int WAVES_N = BN / WN;
    constexpr int LDK = 40;   // 32 + 8 pad; rows stay 16B-aligned (80B stride)
    __shared__ unsigned short Ah[BM][LDK], Al[BM][LDK];
    __shared__ unsigned short Bh[BN][LDK], Bl[BN][LDK];

    const int t = threadIdx.x, lane = t & 63, wave = t >> 6;
    const int wm = (wave / WAVES_N) * WM, wn = (wave % WAVES_N) * WN;
    const int m0 = blockIdx.y * BM, n0 = blockIdx.x * BN;
    const int l15 = lane & 15, l4 = lane >> 4;

    float4v acc[TM][TN];
    #pragma unroll
    for (int i = 0; i < TM; ++i)
        #pragma unroll
        for (int j = 0; j < TN; ++j)
            #pragma unroll
            for (int r = 0; r < 4; ++r) acc[i][j][r] = 0.f;

    for (int k0 = 0; k0 < Kd; k0 += 32) {
        constexpr int ACH = BM * 4 / 256;   // 16B chunks per thread for A
        #pragma unroll
        for (int i = 0; i < ACH; ++i) {
            int idx = t + i * 256;
            int m = idx >> 2, cc = (idx & 3) * 8;
            size_t g = (size_t)(m0 + m) * Kd + k0 + cc;
            *(ushort8v*)&Ah[m][cc] = *(const ushort8v*)&Ahi[g];
            *(ushort8v*)&Al[m][cc] = *(const ushort8v*)&Alo[g];
        }
        constexpr int BCH = BN * 4 / 256;
        #pragma unroll
        for (int i = 0; i < BCH; ++i) {
            int idx = t + i * 256;
            int n = idx >> 2, cc = (idx & 3) * 8;
            size_t g = (size_t)(n0 + n) * Kd + k0 + cc;
            *(ushort8v*)&Bh[n][cc] = *(const ushort8v*)&Whi[g];
            *(ushort8v*)&Bl[n][cc] = *(const ushort8v*)&Wlo[g];
        }
        __syncthreads();

        short8 fa_h[TM], fa_l[TM], fb_h[TN], fb_l[TN];
        #pragma unroll
        for (int im = 0; im < TM; ++im) {
            fa_h[im] = *(const short8*)&Ah[wm + im * 16 + l15][l4 * 8];
            fa_l[im] = *(const short8*)&Al[wm + im * 16 + l15][l4 * 8];
        }
        #pragma unroll
        for (int in = 0; in < TN; ++in) {
            fb_h[in] = *(const short8*)&Bh[wn + in * 16 + l15][l4 * 8];
            fb_l[in] = *(const short8*)&Bl[wn + in * 16 + l15][l4 * 8];
        }
        #pragma unroll
        for (int im = 0; im < TM; ++im)
            #pragma unroll
            for (int in = 0; in < TN; ++in) {
                acc[im][in] = __builtin_amdgcn_mfma_f32_16x16x32_bf16(fa_h[im], fb_h[in], acc[im][in], 0, 0, 0);
                acc[im][in] = __builtin_amdgcn_mfma_f32_16x16x32_bf16(fa_l[im], fb_h[in], acc[im][in], 0, 0, 0);
                acc[im][in] = __builtin_amdgcn_mfma_f32_16x16x32_bf16(fa_h[im], fb_l[in], acc[im][in], 0, 0, 0);
            }
        __syncthreads();
    }

    // epilogue: D row = (lane>>4)*4 + reg, col = lane&15  [m89-verified layout]
    if (mode == 0) {
        #pragma unroll
        for (int in = 0; in < TN; ++in) {
            int n = n0 + wn + in * 16 + l15;
            float bv = bias[n];
            #pragma unroll
            for (int im = 0; im < TM; ++im) {
                int mb = m0 + wm + im * 16 + l4 * 4;
                #pragma unroll
                for (int r = 0; r < 4; ++r)
                    C[(size_t)(mb + r) * N + n] = acc[im][in][r] + bv;
            }
        }
    } else {
        #pragma unroll
        for (int in = 0; in < TN; ++in) {
            int n = n0 + wn + in * 16 + l15;
            int which = n >> 9, h = (n >> 6) & 7, d = n & 63;
            float* dst = (which == 0) ? Qo : (which == 1 ? Ko : Vo);
            float bv = bias[n];
            #pragma unroll
            for (int im = 0; im < TM; ++im) {
                int mb = m0 + wm + im * 16 + l4 * 4;
                #pragma unroll
                for (int r = 0; r < 4; ++r) {
                    int m = mb + r, b = m >> 11, s = m & 2047;
                    dst[(((size_t)b * H_ + h) * S_ + s) * HD_ + d] = acc[im][in][r] + bv;
                }
            }
        }
    }
}

// ---------------------------------------------------------------------------
// Gathered attention, one wave per query, XCD-pinned by (b,h).
// blockIdx.x & 7 selects the XCD (HW round-robins workgroups over the 8
// XCDs); all queries of a given bh land on one XCD so its 2 MB K+V stream
// is fetched from HBM once into that XCD's L2 (Cantor routes are a sliding
// window in s => high L2 reuse across consecutive s).
// ---------------------------------------------------------------------------
__global__ __launch_bounds__(256) void attn_kernel(
    const float* __restrict__ Q, const float* __restrict__ Kp,
    const float* __restrict__ V, const int* __restrict__ routes,
    unsigned short* __restrict__ Ohi, unsigned short* __restrict__ Olo)
{
    __shared__ float q_s[4][64];
    __shared__ float w_s[4][64];
    __shared__ int   r_s[4][64];

    const int wv = threadIdx.x >> 6, lane = threadIdx.x & 63;

    // XCD-aware swizzle: 8192 blocks; xcd = blk&7; 2 bh per xcd; s ordered.
    const int blk  = blockIdx.x;
    const int xcd  = blk & 7;
    const int idx  = blk >> 3;            // [0, 1024)
    const int half = idx >> 9;            // 0 or 1
    const int sblk = idx & 511;           // [0, 512)
    const int bh   = xcd | (half << 3);   // [0, 16)
    const int s    = sblk * 4 + wv;
    const int b    = bh >> 3, h = bh & 7;

    q_s[wv][lane] = Q[((size_t)bh * S_ + s) * HD_ + lane];
    r_s[wv][lane] = routes[s * K_ + lane];
    __syncthreads();

    // phase 1: scores. lane = (key quad p, key-in-pass jl); 4 lanes per key,
    // each lane reads 64B contiguous of the key row.
    const int p = lane & 3, jl = lane >> 2;
    float qv[16];
    #pragma unroll
    for (int i = 0; i < 16; ++i) qv[i] = q_s[wv][p * 16 + i];

    const float* kbase = Kp + (size_t)bh * S_ * HD_;
    #pragma unroll
    for (int pass = 0; pass < 4; ++pass) {
        int j = pass * 16 + jl;
        int rj = r_s[wv][j];
        const float* kp = kbase + (size_t)rj * HD_ + p * 16;
        float partial = 0.f;
        #pragma unroll
        for (int i = 0; i < 16; i += 4) {
            float4 kv = *(const float4*)(kp + i);
            partial += qv[i] * kv.x + qv[i + 1] * kv.y + qv[i + 2] * kv.z + qv[i + 3] * kv.w;
        }
        partial += __shfl_xor(partial, 1);
        partial += __shfl_xor(partial, 2);
        if (p == 0) w_s[wv][j] = partial * 0.125f;
    }
    __syncthreads();

    // softmax over 64 keys (shuffle)
    float sc = w_s[wv][lane];
    float mx = sc;
    #pragma unroll
    for (int off = 32; off >= 1; off >>= 1) mx = fmaxf(mx, __shfl_xor(mx, off));
    float e = __expf(sc - mx);
    float sum = e;
    #pragma unroll
    for (int off = 32; off >= 1; off >>= 1) sum += __shfl_xor(sum, off);
    w_s[wv][lane] = e / sum;
    __syncthreads();

    // phase 2: output d = lane
    const float* vbase = V + (size_t)bh * S_ * HD_;
    float acc = 0.f;
    #pragma unroll 8
    for (int j = 0; j < 64; ++j)
        acc += w_s[wv][j] * vbase[(size_t)r_s[wv][j] * HD_ + lane];

    unsigned short hi = f2bf_rn(acc);
    unsigned short lo = f2bf_rn(acc - bf2f(hi));
    size_t oi = ((size_t)b * S_ + s) * DIM_ + h * HD_ + lane;
    Ohi[oi] = hi;
    Olo[oi] = lo;
}

// ---------------------------------------------------------------------------
// ws layout (bytes):
//   0    Q 8MB | 8M K 8MB | 16M V 8MB | 24M x_hi/attn_hi 4MB | 28M x_lo/attn_lo 4MB
//   32M  Wqkv_hi 1.5M | +1.5M Wqkv_lo | +3M Wout_hi 0.5M | +3.5M Wout_lo
// ---------------------------------------------------------------------------
extern "C" void kernel_launch(void* const* d_in, const int* in_sizes, int n_in,
                              void* d_out, int out_size, void* d_ws, size_t ws_size,
                              hipStream_t stream)
{
    const float* x      = (const float*)d_in[0];
    const float* Wqkv   = (const float*)d_in[1];
    const float* bqkv   = (const float*)d_in[2];
    const float* Wout   = (const float*)d_in[3];
    const float* bout   = (const float*)d_in[4];
    const int*   routes = (const int*)d_in[5];
    float* out = (float*)d_out;

    char* w = (char*)d_ws;
    float* Q  = (float*)(w);
    float* Kp = (float*)(w + (8u << 20));
    float* V  = (float*)(w + (16u << 20));
    unsigned short* xh  = (unsigned short*)(w + (24u << 20));
    unsigned short* xl  = (unsigned short*)(w + (28u << 20));
    unsigned short* ah  = xh;   // aliased: free after qkv gemm
    unsigned short* al  = xl;
    unsigned short* wqh = (unsigned short*)(w + (32u << 20));
    unsigned short* wql = (unsigned short*)(w + (32u << 20) + 1572864u);
    unsigned short* woh = (unsigned short*)(w + (32u << 20) + 3145728u);
    unsigned short* wol = (unsigned short*)(w + (32u << 20) + 3670016u);

    dim3 blk(256);

    prep_x<<<dim3((M_ * DIM_) / (256 * 8)), blk, 0, stream>>>(x, xh, xl);
    prep_w<<<dim3(NQKV_ / 32, DIM_ / 32), blk, 0, stream>>>(Wqkv, wqh, wql, DIM_, NQKV_);
    prep_w<<<dim3(DIM_ / 32, DIM_ / 32), blk, 0, stream>>>(Wout, woh, wol, DIM_, DIM_);

    // qkv: M=4096, N=1536, K=512
    gemm_mfma<128, 128, 64, 64><<<dim3(NQKV_ / 128, M_ / 128), blk, 0, stream>>>(
        xh, xl, wqh, wql, bqkv, nullptr, Q, Kp, V, NQKV_, DIM_, 1);

    attn_kernel<<<dim3((B_ * H_ * S_) / 4), blk, 0, stream>>>(Q, Kp, V, routes, ah, al);

    // out-proj: M=4096, N=512, K=512
    gemm_mfma<64, 128, 64, 32><<<dim3(DIM_ / 128, M_ / 64), blk, 0, stream>>>(
        ah, al, woh, wol, bout, out, nullptr, nullptr, nullptr, DIM_, DIM_, 0);
}